// Round 17
// baseline (128.054 us; speedup 1.0000x reference)
//
#include <hip/hip_runtime.h>

typedef __attribute__((ext_vector_type(8))) short short8;
typedef __attribute__((ext_vector_type(4))) float f32x4;
typedef __attribute__((ext_vector_type(16))) float f32x16;

__device__ __forceinline__ unsigned short f2b(float f) {
  union { float f; unsigned u; } x; x.f = f;
  unsigned r = (x.u + 0x7fffu + ((x.u >> 16) & 1u)) >> 16;
  return (unsigned short)r;
}
__device__ __forceinline__ float b2f(unsigned short b) {
  union { unsigned u; float f; } x; x.u = ((unsigned)b) << 16;
  return x.f;
}
__device__ __forceinline__ unsigned cvtpk(float lo, float hi) {
  unsigned r;
  asm("v_cvt_pk_bf16_f32 %0, %1, %2" : "=v"(r) : "v"(lo), "v"(hi));
  return r;
}
__device__ __forceinline__ void plswap(unsigned& a, unsigned& b) {
  asm volatile("v_permlane32_swap_b32 %0, %1" : "+v"(a), "+v"(b));
}

#define GLDS16(gp, lp)                                                                  \
  __builtin_amdgcn_global_load_lds((const __attribute__((address_space(1))) void*)(gp), \
                                   (__attribute__((address_space(3))) void*)(lp), 16, 0, 0)

// ---------------- fused prep: weight conversion + x transpose ----------------
__global__ __launch_bounds__(256) void prep_kernel(const float* __restrict__ x,
                                                   const float* __restrict__ W_in,
                                                   const float* __restrict__ W_attn,
                                                   const float* __restrict__ W_out,
                                                   unsigned short* __restrict__ Wcat,
                                                   unsigned short* __restrict__ WoutB,
                                                   unsigned short* __restrict__ xT) {
  if (blockIdx.x < 4096) {
    __shared__ float tile[32][33];
    const int bid = blockIdx.x;
    const int b = bid & 7;
    const int rem = bid >> 3;
    const int c0 = (rem >> 5) << 5;
    const int t0 = (rem & 31) << 5;
    const int tj = threadIdx.x & 31, ti = threadIdx.x >> 5;  // ti 0..7
#pragma unroll
    for (int r = 0; r < 32; r += 8)
      tile[ti + r][tj] = x[(((size_t)b << 9) + c0 + ti + r) * 1024 + t0 + tj];
    __syncthreads();
#pragma unroll
    for (int r = 0; r < 32; r += 8)
      xT[(((size_t)b << 10) + t0 + ti + r) * 512 + c0 + tj] = f2b(tile[tj][ti + r]);
  } else {
    const int n1 = 2048 * 512, n2 = 512 * 512, n3 = 512 * 1024;
    for (int i = (blockIdx.x - 4096) * 256 + threadIdx.x; i < n1 + n2 + n3; i += 896 * 256) {
      if (i < n1) Wcat[i] = f2b(W_in[i]);
      else if (i < n1 + n2) Wcat[i] = f2b(W_attn[i - n1]);
      else WoutB[i - n1 - n2] = f2b(W_out[i - n1 - n2]);
    }
  }
}

// ---------------- GEMM A v3: 256m x 128n, 8 waves, BK=32, 3-buf, counted vmcnt ----------------
// Components all individually verified: 64B-row slot swizzle ((row>>1)&3), 3-buf
// single-barrier schedule with vmcnt(3) (tile t+1 in flight at the wait), wave tile
// 64x64 (same frag/acc profile as the proven 128^2 core). 2 blocks/CU (72KB LDS),
// 16 waves/CU; 128 MFMA per barrier (2x the 128^2 core).
__global__ __launch_bounds__(512) void gemm_a_kernel(
    const unsigned short* __restrict__ Wcat, const unsigned short* __restrict__ xT,
    const float* __restrict__ b_in, const float* __restrict__ b_attn,
    const float* __restrict__ w_q, const float* __restrict__ b_q, const float* __restrict__ w_k,
    const float* __restrict__ b_k, unsigned short* __restrict__ u, unsigned short* __restrict__ v,
    unsigned short* __restrict__ qT, unsigned short* __restrict__ kT) {
  __shared__ __align__(16) unsigned short lsA[3 * 8192];  // 3 x 256x32 (16KB each)
  __shared__ __align__(16) unsigned short lsB[3 * 4096];  // 3 x 128x32 (8KB each)
  // 640 blocks = 8 XCD x 80, n-major per XCD: Wcat (2.6MB) + one batch of xT (1MB) per L2
  const int bid = ((blockIdx.x & 7) * 80) + (blockIdx.x >> 3);
  const int n_tile = bid / 10;  // 0..63 (128 flat cols each)
  const int m_tile = bid % 10;  // 0..9 (256 Wcat rows each)
  const int m0 = m_tile << 8;
  const int n0f = n_tile << 7;  // flat col = b*1024 + t
  const int tid = threadIdx.x;
  const int lane = tid & 63;
  const int w = tid >> 6;            // 0..7
  const int wr = w >> 1, wc = w & 1; // wave grid 4(m) x 2(n)
  const int sra = tid >> 2;          // staging row 0..127 (+128 for second A chunk)
  const int ska = (((tid & 3) ^ ((sra >> 1) & 3)) << 3);  // swizzled global k-slot (elems)

  const unsigned short* Ag = Wcat + (size_t)m0 * 512;
  const unsigned short* Bg = xT + (size_t)n0f * 512;

  f32x4 acc[4][4];
  const f32x4 z4 = {0.f, 0.f, 0.f, 0.f};
#pragma unroll
  for (int mi = 0; mi < 4; ++mi)
#pragma unroll
    for (int ni = 0; ni < 4; ++ni) acc[mi][ni] = z4;

#define GA_STAGE(buf, k0)                                                              \
  {                                                                                    \
    GLDS16(Ag + (size_t)sra * 512 + (k0) + ska, (char*)lsA + (buf)*16384 + (tid << 4)); \
    GLDS16(Ag + (size_t)(128 + sra) * 512 + (k0) + ska,                                \
           (char*)lsA + (buf)*16384 + 8192 + (tid << 4));                              \
    GLDS16(Bg + (size_t)sra * 512 + (k0) + ska, (char*)lsB + (buf)*8192 + (tid << 4)); \
  }

  int c0b = 0, c1b = 1, c2b = 2;
  GA_STAGE(0, 0);
  GA_STAGE(1, 32);
  for (int t = 0; t < 16; ++t) {
    if (t + 1 < 16) {
      asm volatile("s_waitcnt vmcnt(3)" ::: "memory");  // tile t landed; t+1 in flight
    } else {
      asm volatile("s_waitcnt vmcnt(0)" ::: "memory");
    }
    __builtin_amdgcn_s_barrier();  // tile t visible block-wide; t-1 reads done
    if (t + 2 < 16) GA_STAGE(c2b, (t + 2) << 5);
    const char* la = (const char*)lsA + c0b * 16384;
    const char* lb = (const char*)lsB + c0b * 8192;
    short8 af[4], bfr[4];
    const int ko = (lane >> 4) << 4;
    const int ra = (wr << 6) + (lane & 15);
    const int rb = (wc << 6) + (lane & 15);
#pragma unroll
    for (int mi = 0; mi < 4; ++mi) {
      const int rowA = ra + (mi << 4);
      af[mi] = *(const short8*)(la + (rowA << 6) + (ko ^ (((rowA >> 1) & 3) << 4)));
    }
#pragma unroll
    for (int ni = 0; ni < 4; ++ni) {
      const int rowB = rb + (ni << 4);
      bfr[ni] = *(const short8*)(lb + (rowB << 6) + (ko ^ (((rowB >> 1) & 3) << 4)));
    }
    __builtin_amdgcn_s_setprio(1);
#pragma unroll
    for (int mi = 0; mi < 4; ++mi)
#pragma unroll
      for (int ni = 0; ni < 4; ++ni)
        acc[mi][ni] =
            __builtin_amdgcn_mfma_f32_16x16x32_bf16(af[mi], bfr[ni], acc[mi][ni], 0, 0, 0);
    __builtin_amdgcn_s_setprio(0);
    const int tmp = c0b; c0b = c1b; c1b = c2b; c2b = tmp;
  }
#undef GA_STAGE

  // ---- epilogue (same math as verified core; m range 256, n range 128) ----
  const int b = n0f >> 10;
  const int tb = n0f & 1023;
#pragma unroll
  for (int mi = 0; mi < 4; ++mi) {
    const int row0 = m0 + (wr << 6) + (mi << 4) + ((lane >> 4) << 2);
#pragma unroll
    for (int ni = 0; ni < 4; ++ni) {
      const int col = tb + (wc << 6) + (ni << 4) + (lane & 15);
      if (row0 < 2048) {
#pragma unroll
        for (int i = 0; i < 4; ++i) {
          const int row = row0 + i;
          const float s = acc[mi][ni][i] + b_in[row];
          const float r = s / (1.f + __expf(-s));  // silu
          if (row < 1024)
            u[((((size_t)b << 10) + row) << 10) + col] = f2b(r);
          else
            v[((((size_t)b << 10) + (row - 1024)) << 10) + col] = f2b(r);
        }
      } else {
        const int c0 = row0 - 2048;
        ushort4 qv, kv;
        unsigned short* qp = (unsigned short*)&qv;
        unsigned short* kp = (unsigned short*)&kv;
#pragma unroll
        for (int i = 0; i < 4; ++i) {
          const int c = c0 + i;
          const float z = acc[mi][ni][i] + b_attn[c];
          qp[i] = f2b(z * w_q[c] + b_q[c]);
          kp[i] = f2b(z * w_k[c] + b_k[c]);
        }
        const int h = c0 >> 6, d = c0 & 63;
        const size_t base = ((((size_t)b * 8 + h) << 10) + col) * 64 + d;
        *(ushort4*)(qT + base) = qv;
        *(ushort4*)(kT + base) = kv;
      }
    }
  }
}

// ---------------- shared GEMM core (128x128, BK=32, 3-buf) for gemm_c ----------------
__device__ __forceinline__ void gemm_stage(const unsigned short* Ag, const unsigned short* Bg,
                                           int lda, int ldb, int k0, unsigned short* lsA,
                                           unsigned short* lsB, int buf, int sr, int sk,
                                           int ldst) {
  const int bb = buf * 8192;  // bytes per buffer
  GLDS16(Ag + (size_t)sr * lda + k0 + sk, (char*)lsA + bb + ldst);
  GLDS16(Ag + (size_t)(sr + 64) * lda + k0 + sk, (char*)lsA + bb + 4096 + ldst);
  GLDS16(Bg + (size_t)sr * ldb + k0 + sk, (char*)lsB + bb + ldst);
  GLDS16(Bg + (size_t)(sr + 64) * ldb + k0 + sk, (char*)lsB + bb + 4096 + ldst);
}

__device__ __forceinline__ void gemm_bt_core(const unsigned short* __restrict__ Ag,
                                             const unsigned short* __restrict__ Bg, int lda,
                                             int ldb, int K, unsigned short* lsA,
                                             unsigned short* lsB, f32x4 acc[4][4]) {
  const int tid = threadIdx.x;
  const int lane = tid & 63;
  const int w = tid >> 6;
  const int wr = w >> 1, wc = w & 1;
  const int sr = tid >> 2;
  const int sk = (((tid & 3) ^ ((sr >> 1) & 3)) << 3);
  const int ldst = (tid >> 6) << 10;

  const int nt = K >> 5;
  int c0b = 0, c1b = 1, c2b = 2;
  gemm_stage(Ag, Bg, lda, ldb, 0, lsA, lsB, 0, sr, sk, ldst);
  gemm_stage(Ag, Bg, lda, ldb, 32, lsA, lsB, 1, sr, sk, ldst);
  for (int t = 0; t < nt; ++t) {
    if (t + 1 < nt) {
      asm volatile("s_waitcnt vmcnt(4)" ::: "memory");
    } else {
      asm volatile("s_waitcnt vmcnt(0)" ::: "memory");
    }
    __builtin_amdgcn_s_barrier();
    if (t + 2 < nt)
      gemm_stage(Ag, Bg, lda, ldb, (t + 2) << 5, lsA, lsB, c2b, sr, sk, ldst);
    short8 af[4], bfr[4];
    const int bb = c0b * 8192;
    const int ko = (lane >> 4) << 4;
    const int ra = (wr << 6) + (lane & 15);
    const int rb = (wc << 6) + (lane & 15);
#pragma unroll
    for (int mi = 0; mi < 4; ++mi) {
      const int rowA = ra + (mi << 4);
      af[mi] = *(const short8*)((const char*)lsA + bb + (rowA << 6) +
                                (ko ^ (((rowA >> 1) & 3) << 4)));
    }
#pragma unroll
    for (int ni = 0; ni < 4; ++ni) {
      const int rowB = rb + (ni << 4);
      bfr[ni] = *(const short8*)((const char*)lsB + bb + (rowB << 6) +
                                 (ko ^ (((rowB >> 1) & 3) << 4)));
    }
#pragma unroll
    for (int mi = 0; mi < 4; ++mi)
#pragma unroll
      for (int ni = 0; ni < 4; ++ni)
        acc[mi][ni] =
            __builtin_amdgcn_mfma_f32_16x16x32_bf16(af[mi], bfr[ni], acc[mi][ni], 0, 0, 0);
    const int tmp = c0b; c0b = c1b; c1b = c2b; c2b = tmp;
  }
}

// ---------------- flash attention v6: T15 double-pipeline (unchanged, verified) ----------------
__global__ __launch_bounds__(256, 2) void attn_kernel(const unsigned short* __restrict__ qT,
                                                      const unsigned short* __restrict__ kT,
                                                      const unsigned short* __restrict__ v,
                                                      const unsigned short* __restrict__ u,
                                                      unsigned short* __restrict__ uoT) {
  __shared__ __align__(16) unsigned short Kls[3 * 4096];
  __shared__ __align__(16) unsigned short Vls[3 * 8192];
  const float SCALE2 = 0.20037430567f;
  const int bx = blockIdx.x;
  const int xcd = bx & 7, idx = bx >> 3;
  const int bh = (xcd << 3) + (idx & 7);
  const int qb = idx >> 3;
  const int b = bh >> 3, h = bh & 7;
  const int tid = threadIdx.x;
  const int lane = tid & 63;
  const int w = tid >> 6;
  const int l5 = lane >> 5;
  const int l31 = lane & 31;
  const int q0 = qb << 7;

  const unsigned short* qh = qT + ((size_t)bh << 16);
  const unsigned short* kh = kT + ((size_t)bh << 16);
  const unsigned short* vh = v + ((((size_t)b << 10) + (h << 7)) << 10);

  short8 qf[4];
#pragma unroll
  for (int ds = 0; ds < 4; ++ds)
    qf[ds] = *(const short8*)(qh + (size_t)(q0 + (w << 5) + l31) * 64 + (ds << 4) + (l5 << 3));

  f32x16 o[4];
#pragma unroll
  for (int eb = 0; eb < 4; ++eb)
#pragma unroll
    for (int i = 0; i < 16; ++i) o[eb][i] = 0.f;
  float lacc = 0.f;

  const int srow = tid >> 3;
  const int scol = (((tid & 7) ^ (srow & 7)) << 3);

#define ATTN_STAGE(buf, kt)                                                            \
  {                                                                                    \
    const int t2 = (kt) << 6;                                                          \
    char* kbase = (char*)Kls + (buf)*8192;                                             \
    char* vbase = (char*)Vls + (buf)*16384;                                            \
    GLDS16(kh + (size_t)(t2 + srow) * 64 + scol, kbase + (w << 10));                   \
    GLDS16(kh + (size_t)(t2 + 32 + srow) * 64 + scol, kbase + 4096 + (w << 10));       \
    GLDS16(vh + ((size_t)srow << 10) + t2 + scol, vbase + (w << 10));                  \
    GLDS16(vh + ((size_t)(32 + srow) << 10) + t2 + scol, vbase + 4096 + (w << 10));    \
    GLDS16(vh + ((size_t)(64 + srow) << 10) + t2 + scol, vbase + 8192 + (w << 10));    \
    GLDS16(vh + ((size_t)(96 + srow) << 10) + t2 + scol, vbase + 12288 + (w << 10));   \
  }

#define KREAD(kbp, kr, ds)                                                             \
  (*(const short8*)((kbp) + ((kr) << 7) + ((((ds) << 5) + (l5 << 4)) ^ (((kr)&7) << 4))))
#define VREAD(vbp, vrow, ks)                                                           \
  (*(const short8*)((vbp) + ((vrow) << 7) + ((((ks) << 5) + (l5 << 4)) ^ (((vrow)&7) << 4))))

#define PACK(sv, out0, out1)                                                           \
  do {                                                                                 \
    float p_[16];                                                                      \
    _Pragma("unroll") for (int i_ = 0; i_ < 16; ++i_) {                                \
      p_[i_] = exp2f(sv[i_] * SCALE2);                                                 \
      lacc += p_[i_];                                                                  \
    }                                                                                  \
    unsigned W00 = cvtpk(p_[0], p_[1]), W01 = cvtpk(p_[2], p_[3]);                     \
    unsigned W10 = cvtpk(p_[4], p_[5]), W11 = cvtpk(p_[6], p_[7]);                     \
    unsigned W20 = cvtpk(p_[8], p_[9]), W21 = cvtpk(p_[10], p_[11]);                   \
    unsigned W30 = cvtpk(p_[12], p_[13]), W31 = cvtpk(p_[14], p_[15]);                 \
    unsigned a_ = W10, b_ = W00;                                                       \
    plswap(a_, b_);                                                                    \
    (out0).u4[0] = b_; (out0).u4[2] = a_;                                              \
    unsigned c_ = W11, d_ = W01;                                                       \
    plswap(c_, d_);                                                                    \
    (out0).u4[1] = d_; (out0).u4[3] = c_;                                              \
    unsigned e_ = W30, f_ = W20;                                                       \
    plswap(e_, f_);                                                                    \
    (out1).u4[0] = f_; (out1).u4[2] = e_;                                              \
    unsigned g_ = W31, h_ = W21;                                                       \
    plswap(g_, h_);                                                                    \
    (out1).u4[1] = h_; (out1).u4[3] = g_;                                              \
  } while (0)

  union U8 { short8 s8; unsigned u4[4]; };
  U8 pfP[4];

  ATTN_STAGE(0, 0);
  ATTN_STAGE(1, 1);

  asm volatile("s_waitcnt vmcnt(6)" ::: "memory");
  __builtin_amdgcn_s_barrier();
  {
    const char* kb = (const char*)Kls;
    f32x16 s0, s1;
#pragma unroll
    for (int i = 0; i < 16; ++i) { s0[i] = 0.f; s1[i] = 0.f; }
    __builtin_amdgcn_s_setprio(1);
#pragma unroll
    for (int ds = 0; ds < 4; ++ds) {
      short8 kfA = KREAD(kb, l31, ds);
      s0 = __builtin_amdgcn_mfma_f32_32x32x16_bf16(kfA, qf[ds], s0, 0, 0, 0);
      short8 kfB = KREAD(kb, 32 + l31, ds);
      s1 = __builtin_amdgcn_mfma_f32_32x32x16_bf16(kfB, qf[ds], s1, 0, 0, 0);
    }
    __builtin_amdgcn_s_setprio(0);
    PACK(s0, pfP[0], pfP[1]);
    PACK(s1, pfP[2], pfP[3]);
  }
  __builtin_amdgcn_s_barrier();
  ATTN_STAGE(2, 2);

  int ck = 1, cv = 0;
  for (int kt = 1; kt < 16; ++kt) {
    if (kt < 15) {
      asm volatile("s_waitcnt vmcnt(6)" ::: "memory");
    } else {
      asm volatile("s_waitcnt vmcnt(0)" ::: "memory");
    }
    __builtin_amdgcn_s_barrier();

    const char* kb = (const char*)Kls + ck * 8192;
    const char* vb = (const char*)Vls + cv * 16384;

    short8 kfA[4], kfB[4];
#pragma unroll
    for (int ds = 0; ds < 4; ++ds) {
      kfA[ds] = KREAD(kb, l31, ds);
      kfB[ds] = KREAD(kb, 32 + l31, ds);
    }

    f32x16 s0, s1;
#pragma unroll
    for (int i = 0; i < 16; ++i) { s0[i] = 0.f; s1[i] = 0.f; }
    __builtin_amdgcn_s_setprio(1);
#pragma unroll
    for (int ks = 0; ks < 4; ++ks) {
      s0 = __builtin_amdgcn_mfma_f32_32x32x16_bf16(kfA[ks], qf[ks], s0, 0, 0, 0);
      s1 = __builtin_amdgcn_mfma_f32_32x32x16_bf16(kfB[ks], qf[ks], s1, 0, 0, 0);
#pragma unroll
      for (int eb = 0; eb < 4; ++eb) {
        short8 vf = VREAD(vb, (eb << 5) + l31, ks);
        o[eb] = __builtin_amdgcn_mfma_f32_32x32x16_bf16(vf, pfP[ks].s8, o[eb], 0, 0, 0);
      }
    }
    __builtin_amdgcn_s_setprio(0);

    U8 pfN[4];
    PACK(s0, pfN[0], pfN[1]);
    PACK(s1, pfN[2], pfN[3]);
#pragma unroll
    for (int i = 0; i < 4; ++i) pfP[i] = pfN[i];

    if (kt + 2 < 16) {
      __builtin_amdgcn_s_barrier();
      ATTN_STAGE(cv, kt + 2);
    }
    const int third = 3 - ck - cv;
    cv = ck;
    ck = third;
  }

  {
    const char* vb = (const char*)Vls + cv * 16384;
    __builtin_amdgcn_s_setprio(1);
#pragma unroll
    for (int ks = 0; ks < 4; ++ks) {
#pragma unroll
      for (int eb = 0; eb < 4; ++eb) {
        short8 vf = VREAD(vb, (eb << 5) + l31, ks);
        o[eb] = __builtin_amdgcn_mfma_f32_32x32x16_bf16(vf, pfP[ks].s8, o[eb], 0, 0, 0);
      }
    }
    __builtin_amdgcn_s_setprio(0);
  }
#undef ATTN_STAGE
#undef KREAD
#undef VREAD
#undef PACK

  lacc += __shfl_xor(lacc, 32, 64);
  const float rl = 1.f / lacc;
  const int t = q0 + (w << 5) + l31;

#pragma unroll
  for (int eb = 0; eb < 4; ++eb) {
#pragma unroll
    for (int g = 0; g < 4; ++g) {
      const int e4 = (eb << 5) + (g << 3) + (l5 << 2);
      const int eg = (h << 7) + e4;
      ushort4 outv;
      unsigned short* op = (unsigned short*)&outv;
#pragma unroll
      for (int j = 0; j < 4; ++j) {
        const int i = (g << 2) + j;
        const float oo = o[eb][i] * rl;
        const float uu = b2f(u[((((size_t)b << 10) + eg + j) << 10) + t]);
        op[j] = f2b(oo * uu);
      }
      *(ushort4*)(uoT + ((((size_t)b << 10) + t) << 10) + eg) = outv;
    }
  }
}

// ---------------- GEMM C: out^T = uoT(1024x1024) @ W_out^T, +bias+residual -> y(bf16) ----------------
__global__ __launch_bounds__(256) void gemm_c_kernel(const unsigned short* __restrict__ uoT,
                                                     const unsigned short* __restrict__ WoutB,
                                                     const float* __restrict__ x,
                                                     const float* __restrict__ b_out,
                                                     unsigned short* __restrict__ y) {
  __shared__ __align__(16) unsigned short lsA[12288];
  __shared__ __align__(16) unsigned short lsB[12288];
  const int bid = ((blockIdx.x & 7) * 32) + (blockIdx.x >> 3);
  const int b = bid >> 5;
  const int rem = bid & 31;
  const int m0 = (rem >> 2) << 7;
  const int n0 = (rem & 3) << 7;
  f32x4 acc[4][4];
  const f32x4 z4 = {0.f, 0.f, 0.f, 0.f};
#pragma unroll
  for (int mi = 0; mi < 4; ++mi)
#pragma unroll
    for (int ni = 0; ni < 4; ++ni) acc[mi][ni] = z4;

  const unsigned short* Ag = uoT + ((size_t)b << 20) + ((size_t)m0 << 10);
  const unsigned short* Bg = WoutB + ((size_t)n0 << 10);
  gemm_bt_core(Ag, Bg, 1024, 1024, 1024, lsA, lsB, acc);

  const int lane = threadIdx.x & 63;
  const int w = threadIdx.x >> 6;
  const int wr = w >> 1, wc = w & 1;
#pragma unroll
  for (int mi = 0; mi < 4; ++mi) {
    const int t4 = m0 + (wr << 6) + (mi << 4) + ((lane >> 4) << 2);
#pragma unroll
    for (int ni = 0; ni < 4; ++ni) {
      const int c = n0 + (wc << 6) + (ni << 4) + (lane & 15);
      const size_t base = ((((size_t)b << 9) + c) << 10) + t4;
      const f32x4 xv = *(const f32x4*)(x + base);
      const float bo = b_out[c];
      ushort4 ov;
      unsigned short* op = (unsigned short*)&ov;
#pragma unroll
      for (int i = 0; i < 4; ++i) op[i] = f2b(acc[mi][ni][i] + bo + xv[i]);
      *(ushort4*)(y + base) = ov;
    }
  }
}

// ---------------- RMSNorm over C per (b,t): y bf16 in, f32 out ----------------
__global__ __launch_bounds__(256) void rms_kernel(const unsigned short* __restrict__ y,
                                                  const float* __restrict__ gamma,
                                                  float* __restrict__ out) {
  __shared__ float part[8][32];
  __shared__ float rmsv[32];
  const int bid = blockIdx.x;
  const int b = bid >> 5;
  const int t0 = (bid & 31) << 5;
  const int tid = threadIdx.x;
  const int tt = tid & 31, cg = tid >> 5;
  const int t = t0 + tt;
  float vals[64];
  float ss = 0.f;
#pragma unroll
  for (int ci = 0; ci < 64; ++ci) {
    const int c = (cg << 6) + ci;
    const float vv = b2f(y[((((size_t)b << 9) + c) << 10) + t]);
    vals[ci] = vv;
    ss += vv * vv;
  }
  part[cg][tt] = ss;
  __syncthreads();
  if (tid < 32) {
    float tot = 0.f;
#pragma unroll
    for (int g = 0; g < 8; ++g) tot += part[g][tid];
    rmsv[tid] = rsqrtf(tot / 512.f + 1e-5f);
  }
  __syncthreads();
  const float rm = rmsv[tt];
#pragma unroll
  for (int ci = 0; ci < 64; ++ci) {
    const int c = (cg << 6) + ci;
    out[((((size_t)b << 9) + c) << 10) + t] = vals[ci] * rm * gamma[c];
  }
}

extern "C" void kernel_launch(void* const* d_in, const int* in_sizes, int n_in, void* d_out,
                              int out_size, void* d_ws, size_t ws_size, hipStream_t stream) {
  const float* x = (const float*)d_in[0];
  const float* W_in = (const float*)d_in[1];
  const float* b_in = (const float*)d_in[2];
  const float* W_attn = (const float*)d_in[3];
  const float* b_attn = (const float*)d_in[4];
  const float* w_q = (const float*)d_in[5];
  const float* b_q = (const float*)d_in[6];
  const float* w_k = (const float*)d_in[7];
  const float* b_k = (const float*)d_in[8];
  const float* W_out = (const float*)d_in[9];
  const float* b_out = (const float*)d_in[10];
  const float* gamma = (const float*)d_in[11];
  float* out = (float*)d_out;

  char* ws = (char*)d_ws;
  size_t off = 0;
  auto alloc = [&](size_t bytes) {
    char* p = ws + off;
    off += (bytes + 255) & ~(size_t)255;
    return p;
  };
  unsigned short* Wcat = (unsigned short*)alloc((size_t)2560 * 512 * 2);
  unsigned short* WoutB = (unsigned short*)alloc((size_t)512 * 1024 * 2);
  unsigned short* xT = (unsigned short*)alloc((size_t)8 * 1024 * 512 * 2);
  unsigned short* u = (unsigned short*)alloc((size_t)8 * 1024 * 1024 * 2);
  unsigned short* v = (unsigned short*)alloc((size_t)8 * 1024 * 1024 * 2);
  unsigned short* qT = (unsigned short*)alloc((size_t)8 * 8 * 1024 * 64 * 2);
  unsigned short* kT = (unsigned short*)alloc((size_t)8 * 8 * 1024 * 64 * 2);
  unsigned short* uoT = (unsigned short*)alloc((size_t)8 * 1024 * 1024 * 2);
  unsigned short* y = (unsigned short*)alloc((size_t)8 * 512 * 1024 * 2);
  if (off > ws_size) return;  // fail visibly (poisoned output)

  prep_kernel<<<4992, 256, 0, stream>>>(x, W_in, W_attn, W_out, Wcat, WoutB, xT);
  gemm_a_kernel<<<640, 512, 0, stream>>>(Wcat, xT, b_in, b_attn, w_q, b_q, w_k, b_k, u, v, qT,
                                         kT);
  attn_kernel<<<512, 256, 0, stream>>>(qT, kT, v, u, uoT);
  gemm_c_kernel<<<256, 256, 0, stream>>>(uoT, WoutB, x, b_out, y);
  rms_kernel<<<256, 256, 0, stream>>>(y, gamma, out);
}

// Round 18
// 121.015 us; speedup vs baseline: 1.0582x; 1.0582x over previous
//
#include <hip/hip_runtime.h>

typedef __attribute__((ext_vector_type(8))) short short8;
typedef __attribute__((ext_vector_type(4))) float f32x4;
typedef __attribute__((ext_vector_type(16))) float f32x16;

__device__ __forceinline__ unsigned short f2b(float f) {
  union { float f; unsigned u; } x; x.f = f;
  unsigned r = (x.u + 0x7fffu + ((x.u >> 16) & 1u)) >> 16;
  return (unsigned short)r;
}
__device__ __forceinline__ float b2f(unsigned short b) {
  union { unsigned u; float f; } x; x.u = ((unsigned)b) << 16;
  return x.f;
}
__device__ __forceinline__ unsigned cvtpk(float lo, float hi) {
  unsigned r;
  asm("v_cvt_pk_bf16_f32 %0, %1, %2" : "=v"(r) : "v"(lo), "v"(hi));
  return r;
}
__device__ __forceinline__ void plswap(unsigned& a, unsigned& b) {
  asm volatile("v_permlane32_swap_b32 %0, %1" : "+v"(a), "+v"(b));
}

#define GLDS16(gp, lp)                                                                  \
  __builtin_amdgcn_global_load_lds((const __attribute__((address_space(1))) void*)(gp), \
                                   (__attribute__((address_space(3))) void*)(lp), 16, 0, 0)

// ---------------- fused prep: weight conversion + x transpose ----------------
__global__ __launch_bounds__(256) void prep_kernel(const float* __restrict__ x,
                                                   const float* __restrict__ W_in,
                                                   const float* __restrict__ W_attn,
                                                   const float* __restrict__ W_out,
                                                   unsigned short* __restrict__ Wcat,
                                                   unsigned short* __restrict__ WoutB,
                                                   unsigned short* __restrict__ xT) {
  if (blockIdx.x < 4096) {
    // transpose: xT[b][t][c] = bf16(x[b][c][t]); b = bid&7 aligns batch to XCD
    __shared__ float tile[32][33];
    const int bid = blockIdx.x;
    const int b = bid & 7;
    const int rem = bid >> 3;
    const int c0 = (rem >> 5) << 5;
    const int t0 = (rem & 31) << 5;
    const int tj = threadIdx.x & 31, ti = threadIdx.x >> 5;  // ti 0..7
#pragma unroll
    for (int r = 0; r < 32; r += 8)
      tile[ti + r][tj] = x[(((size_t)b << 9) + c0 + ti + r) * 1024 + t0 + tj];
    __syncthreads();
#pragma unroll
    for (int r = 0; r < 32; r += 8)
      xT[(((size_t)b << 10) + t0 + ti + r) * 512 + c0 + tj] = f2b(tile[tj][ti + r]);
  } else {
    const int n1 = 2048 * 512, n2 = 512 * 512, n3 = 512 * 1024;
    for (int i = (blockIdx.x - 4096) * 256 + threadIdx.x; i < n1 + n2 + n3; i += 896 * 256) {
      if (i < n1) Wcat[i] = f2b(W_in[i]);
      else if (i < n1 + n2) Wcat[i] = f2b(W_attn[i - n1]);
      else WoutB[i - n1 - n2] = f2b(W_out[i - n1 - n2]);
    }
  }
}

// ---------------- shared GEMM core: 128x128 tile, BK=32, 4 waves, 3-buf, 1 barrier/step ----------------
// Slot swizzle (verified: conflicts 2.6M -> 0): LDS[row][slot s] holds global k-slot
// s ^ ((row>>1)&3); stage pre-swizzles the GLOBAL source col (dest linear, as
// global_load_lds requires); reads XOR the same. Counted vmcnt(4) keeps tile t+1's
// loads in flight across the barrier (T4).
__device__ __forceinline__ void gemm_stage(const unsigned short* Ag, const unsigned short* Bg,
                                           int lda, int ldb, int k0, unsigned short* lsA,
                                           unsigned short* lsB, int buf, int sr, int sk,
                                           int ldst) {
  const int bb = buf * 8192;  // bytes per buffer
  GLDS16(Ag + (size_t)sr * lda + k0 + sk, (char*)lsA + bb + ldst);
  GLDS16(Ag + (size_t)(sr + 64) * lda + k0 + sk, (char*)lsA + bb + 4096 + ldst);
  GLDS16(Bg + (size_t)sr * ldb + k0 + sk, (char*)lsB + bb + ldst);
  GLDS16(Bg + (size_t)(sr + 64) * ldb + k0 + sk, (char*)lsB + bb + 4096 + ldst);
}

__device__ __forceinline__ void gemm_bt_core(const unsigned short* __restrict__ Ag,
                                             const unsigned short* __restrict__ Bg, int lda,
                                             int ldb, int K, unsigned short* lsA,
                                             unsigned short* lsB, f32x4 acc[4][4]) {
  const int tid = threadIdx.x;
  const int lane = tid & 63;
  const int w = tid >> 6;
  const int wr = w >> 1, wc = w & 1;
  const int sr = tid >> 2;  // staging row 0..63 (row sr and sr+64 share (sr>>1)&3 mod 4)
  const int sk = (((tid & 3) ^ ((sr >> 1) & 3)) << 3);  // swizzled global k-slot (elems)
  const int ldst = (tid >> 6) << 10;  // wave-uniform LDS byte base

  const int nt = K >> 5;
  int c0b = 0, c1b = 1, c2b = 2;
  gemm_stage(Ag, Bg, lda, ldb, 0, lsA, lsB, 0, sr, sk, ldst);
  gemm_stage(Ag, Bg, lda, ldb, 32, lsA, lsB, 1, sr, sk, ldst);
  for (int t = 0; t < nt; ++t) {
    if (t + 1 < nt) {
      asm volatile("s_waitcnt vmcnt(4)" ::: "memory");  // tile t landed (t+1 in flight)
    } else {
      asm volatile("s_waitcnt vmcnt(0)" ::: "memory");
    }
    __builtin_amdgcn_s_barrier();  // tile t visible block-wide; t-1 reads done
    if (t + 2 < nt)
      gemm_stage(Ag, Bg, lda, ldb, (t + 2) << 5, lsA, lsB, c2b, sr, sk, ldst);
    short8 af[4], bfr[4];
    const int bb = c0b * 8192;
    const int ko = (lane >> 4) << 4;  // byte slot within 64B row
    const int ra = (wr << 6) + (lane & 15);
    const int rb = (wc << 6) + (lane & 15);
#pragma unroll
    for (int mi = 0; mi < 4; ++mi) {
      const int rowA = ra + (mi << 4);
      af[mi] = *(const short8*)((const char*)lsA + bb + (rowA << 6) +
                                (ko ^ (((rowA >> 1) & 3) << 4)));
    }
#pragma unroll
    for (int ni = 0; ni < 4; ++ni) {
      const int rowB = rb + (ni << 4);
      bfr[ni] = *(const short8*)((const char*)lsB + bb + (rowB << 6) +
                                 (ko ^ (((rowB >> 1) & 3) << 4)));
    }
#pragma unroll
    for (int mi = 0; mi < 4; ++mi)
#pragma unroll
      for (int ni = 0; ni < 4; ++ni)
        acc[mi][ni] =
            __builtin_amdgcn_mfma_f32_16x16x32_bf16(af[mi], bfr[ni], acc[mi][ni], 0, 0, 0);
    const int tmp = c0b; c0b = c1b; c1b = c2b; c2b = tmp;
  }
}

// ---------------- GEMM A: [W_in;W_attn](2560x512) @ x[b](512x1024) ----------------
__global__ __launch_bounds__(256) void gemm_a_kernel(
    const unsigned short* __restrict__ Wcat, const unsigned short* __restrict__ xT,
    const float* __restrict__ b_in, const float* __restrict__ b_attn,
    const float* __restrict__ w_q, const float* __restrict__ b_q, const float* __restrict__ w_k,
    const float* __restrict__ b_k, unsigned short* __restrict__ u, unsigned short* __restrict__ v,
    unsigned short* __restrict__ qT, unsigned short* __restrict__ kT) {
  __shared__ __align__(16) unsigned short lsA[12288];  // 3 x 8KB
  __shared__ __align__(16) unsigned short lsB[12288];
  // XCD swizzle: 1280 = 8 XCDs x 160; each XCD owns one batch b (W+x ~3.6MB fits L2)
  const int bid = ((blockIdx.x & 7) * 160) + (blockIdx.x >> 3);
  const int b = bid / 160;
  const int rem = bid % 160;
  const int m0 = (rem >> 3) << 7;
  const int n0 = (rem & 7) << 7;
  f32x4 acc[4][4];
  const f32x4 z4 = {0.f, 0.f, 0.f, 0.f};
#pragma unroll
  for (int mi = 0; mi < 4; ++mi)
#pragma unroll
    for (int ni = 0; ni < 4; ++ni) acc[mi][ni] = z4;

  const unsigned short* Ag = Wcat + (size_t)m0 * 512;
  const unsigned short* Bg = xT + ((size_t)b << 19) + ((size_t)n0 << 9);
  gemm_bt_core(Ag, Bg, 512, 512, 512, lsA, lsB, acc);

  const int lane = threadIdx.x & 63;
  const int w = threadIdx.x >> 6;
  const int wr = w >> 1, wc = w & 1;
#pragma unroll
  for (int mi = 0; mi < 4; ++mi) {
    const int row0 = m0 + (wr << 6) + (mi << 4) + ((lane >> 4) << 2);
#pragma unroll
    for (int ni = 0; ni < 4; ++ni) {
      const int col = n0 + (wc << 6) + (ni << 4) + (lane & 15);
      if (row0 < 2048) {
#pragma unroll
        for (int i = 0; i < 4; ++i) {
          const int row = row0 + i;
          const float s = acc[mi][ni][i] + b_in[row];
          const float r = s / (1.f + __expf(-s));  // silu
          if (row < 1024)
            u[((((size_t)b << 10) + row) << 10) + col] = f2b(r);
          else
            v[((((size_t)b << 10) + (row - 1024)) << 10) + col] = f2b(r);
        }
      } else {
        const int c0 = row0 - 2048;
        ushort4 qv, kv;
        unsigned short* qp = (unsigned short*)&qv;
        unsigned short* kp = (unsigned short*)&kv;
#pragma unroll
        for (int i = 0; i < 4; ++i) {
          const int c = c0 + i;
          const float z = acc[mi][ni][i] + b_attn[c];
          qp[i] = f2b(z * w_q[c] + b_q[c]);
          kp[i] = f2b(z * w_k[c] + b_k[c]);
        }
        const int h = c0 >> 6, d = c0 & 63;
        const size_t base = ((((size_t)b * 8 + h) << 10) + col) * 64 + d;
        *(ushort4*)(qT + base) = qv;
        *(ushort4*)(kT + base) = kv;
      }
    }
  }
}

// ---------------- flash attention v6: T15 double-pipeline (PV consumes prev tile's P) ----------------
__global__ __launch_bounds__(256, 2) void attn_kernel(const unsigned short* __restrict__ qT,
                                                      const unsigned short* __restrict__ kT,
                                                      const unsigned short* __restrict__ v,
                                                      const unsigned short* __restrict__ u,
                                                      unsigned short* __restrict__ uoT) {
  __shared__ __align__(16) unsigned short Kls[3 * 4096];  // 3 x [64 k][64 d] swizzled
  __shared__ __align__(16) unsigned short Vls[3 * 8192];  // 3 x [128 e][64 t] swizzled
  const float SCALE2 = 0.20037430567f;  // (log(1024)/log(512)/sqrt(64)) * log2(e)
  const int bx = blockIdx.x;
  const int xcd = bx & 7, idx = bx >> 3;  // idx 0..63
  const int bh = (xcd << 3) + (idx & 7);
  const int qb = idx >> 3;  // 0..7
  const int b = bh >> 3, h = bh & 7;
  const int tid = threadIdx.x;
  const int lane = tid & 63;
  const int w = tid >> 6;  // qw 0..3
  const int l5 = lane >> 5;
  const int l31 = lane & 31;
  const int q0 = qb << 7;

  const unsigned short* qh = qT + ((size_t)bh << 16);
  const unsigned short* kh = kT + ((size_t)bh << 16);
  const unsigned short* vh = v + ((((size_t)b << 10) + (h << 7)) << 10);

  short8 qf[4];
#pragma unroll
  for (int ds = 0; ds < 4; ++ds)
    qf[ds] = *(const short8*)(qh + (size_t)(q0 + (w << 5) + l31) * 64 + (ds << 4) + (l5 << 3));

  f32x16 o[4];
#pragma unroll
  for (int eb = 0; eb < 4; ++eb)
#pragma unroll
    for (int i = 0; i < 16; ++i) o[eb][i] = 0.f;
  float lacc = 0.f;

  const int srow = tid >> 3;                         // 0..31
  const int scol = (((tid & 7) ^ (srow & 7)) << 3);  // pre-swizzled src col (elems)

#define ATTN_STAGE(buf, kt)                                                            \
  {                                                                                    \
    const int t2 = (kt) << 6;                                                          \
    char* kbase = (char*)Kls + (buf)*8192;                                             \
    char* vbase = (char*)Vls + (buf)*16384;                                            \
    GLDS16(kh + (size_t)(t2 + srow) * 64 + scol, kbase + (w << 10));                   \
    GLDS16(kh + (size_t)(t2 + 32 + srow) * 64 + scol, kbase + 4096 + (w << 10));       \
    GLDS16(vh + ((size_t)srow << 10) + t2 + scol, vbase + (w << 10));                  \
    GLDS16(vh + ((size_t)(32 + srow) << 10) + t2 + scol, vbase + 4096 + (w << 10));    \
    GLDS16(vh + ((size_t)(64 + srow) << 10) + t2 + scol, vbase + 8192 + (w << 10));    \
    GLDS16(vh + ((size_t)(96 + srow) << 10) + t2 + scol, vbase + 12288 + (w << 10));   \
  }

#define KREAD(kbp, kr, ds)                                                             \
  (*(const short8*)((kbp) + ((kr) << 7) + ((((ds) << 5) + (l5 << 4)) ^ (((kr)&7) << 4))))
#define VREAD(vbp, vrow, ks)                                                           \
  (*(const short8*)((vbp) + ((vrow) << 7) + ((((ks) << 5) + (l5 << 4)) ^ (((vrow)&7) << 4))))

#define PACK(sv, out0, out1)                                                           \
  do {                                                                                 \
    float p_[16];                                                                      \
    _Pragma("unroll") for (int i_ = 0; i_ < 16; ++i_) {                                \
      p_[i_] = exp2f(sv[i_] * SCALE2);                                                 \
      lacc += p_[i_];                                                                  \
    }                                                                                  \
    unsigned W00 = cvtpk(p_[0], p_[1]), W01 = cvtpk(p_[2], p_[3]);                     \
    unsigned W10 = cvtpk(p_[4], p_[5]), W11 = cvtpk(p_[6], p_[7]);                     \
    unsigned W20 = cvtpk(p_[8], p_[9]), W21 = cvtpk(p_[10], p_[11]);                   \
    unsigned W30 = cvtpk(p_[12], p_[13]), W31 = cvtpk(p_[14], p_[15]);                 \
    unsigned a_ = W10, b_ = W00;                                                       \
    plswap(a_, b_);                                                                    \
    (out0).u4[0] = b_; (out0).u4[2] = a_;                                              \
    unsigned c_ = W11, d_ = W01;                                                       \
    plswap(c_, d_);                                                                    \
    (out0).u4[1] = d_; (out0).u4[3] = c_;                                              \
    unsigned e_ = W30, f_ = W20;                                                       \
    plswap(e_, f_);                                                                    \
    (out1).u4[0] = f_; (out1).u4[2] = e_;                                              \
    unsigned g_ = W31, h_ = W21;                                                       \
    plswap(g_, h_);                                                                    \
    (out1).u4[1] = h_; (out1).u4[3] = g_;                                              \
  } while (0)

  union U8 { short8 s8; unsigned u4[4]; };
  U8 pfP[4];

  ATTN_STAGE(0, 0);
  ATTN_STAGE(1, 1);

  // ---- iter 0: QK(0) + pack only ----
  asm volatile("s_waitcnt vmcnt(6)" ::: "memory");
  __builtin_amdgcn_s_barrier();
  {
    const char* kb = (const char*)Kls;
    f32x16 s0, s1;
#pragma unroll
    for (int i = 0; i < 16; ++i) { s0[i] = 0.f; s1[i] = 0.f; }
    __builtin_amdgcn_s_setprio(1);
#pragma unroll
    for (int ds = 0; ds < 4; ++ds) {
      short8 kfA = KREAD(kb, l31, ds);
      s0 = __builtin_amdgcn_mfma_f32_32x32x16_bf16(kfA, qf[ds], s0, 0, 0, 0);
      short8 kfB = KREAD(kb, 32 + l31, ds);
      s1 = __builtin_amdgcn_mfma_f32_32x32x16_bf16(kfB, qf[ds], s1, 0, 0, 0);
    }
    __builtin_amdgcn_s_setprio(0);
    PACK(s0, pfP[0], pfP[1]);
    PACK(s1, pfP[2], pfP[3]);
  }
  __builtin_amdgcn_s_barrier();
  ATTN_STAGE(2, 2);

  int ck = 1, cv = 0;  // ck = kt%3, cv = (kt-1)%3
  for (int kt = 1; kt < 16; ++kt) {
    if (kt < 15) {
      asm volatile("s_waitcnt vmcnt(6)" ::: "memory");  // tile kt landed
    } else {
      asm volatile("s_waitcnt vmcnt(0)" ::: "memory");
    }
    __builtin_amdgcn_s_barrier();  // K/V[kt] visible to all waves

    const char* kb = (const char*)Kls + ck * 8192;
    const char* vb = (const char*)Vls + cv * 16384;

    // preload K fragments
    short8 kfA[4], kfB[4];
#pragma unroll
    for (int ds = 0; ds < 4; ++ds) {
      kfA[ds] = KREAD(kb, l31, ds);
      kfB[ds] = KREAD(kb, 32 + l31, ds);
    }

    // ---- interleaved: QK(kt) (8 MFMA) || PV(kt-1) (16 MFMA) ----
    f32x16 s0, s1;
#pragma unroll
    for (int i = 0; i < 16; ++i) { s0[i] = 0.f; s1[i] = 0.f; }
    __builtin_amdgcn_s_setprio(1);
#pragma unroll
    for (int ks = 0; ks < 4; ++ks) {
      s0 = __builtin_amdgcn_mfma_f32_32x32x16_bf16(kfA[ks], qf[ks], s0, 0, 0, 0);
      s1 = __builtin_amdgcn_mfma_f32_32x32x16_bf16(kfB[ks], qf[ks], s1, 0, 0, 0);
#pragma unroll
      for (int eb = 0; eb < 4; ++eb) {
        short8 vf = VREAD(vb, (eb << 5) + l31, ks);
        o[eb] = __builtin_amdgcn_mfma_f32_32x32x16_bf16(vf, pfP[ks].s8, o[eb], 0, 0, 0);
      }
    }
    __builtin_amdgcn_s_setprio(0);

    // ---- pack(kt) -> pfP (feeds next iter's PV) ----
    U8 pfN[4];
    PACK(s0, pfN[0], pfN[1]);
    PACK(s1, pfN[2], pfN[3]);
#pragma unroll
    for (int i = 0; i < 4; ++i) pfP[i] = pfN[i];

    if (kt + 2 < 16) {
      __builtin_amdgcn_s_barrier();  // all waves done reading V[kt-1] / K[kt-1]
      ATTN_STAGE(cv, kt + 2);        // (kt+2)%3 == cv
    }
    const int third = 3 - ck - cv;
    cv = ck;
    ck = third;
  }

  // ---- tail: PV(15) ----
  {
    const char* vb = (const char*)Vls + cv * 16384;
    __builtin_amdgcn_s_setprio(1);
#pragma unroll
    for (int ks = 0; ks < 4; ++ks) {
#pragma unroll
      for (int eb = 0; eb < 4; ++eb) {
        short8 vf = VREAD(vb, (eb << 5) + l31, ks);
        o[eb] = __builtin_amdgcn_mfma_f32_32x32x16_bf16(vf, pfP[ks].s8, o[eb], 0, 0, 0);
      }
    }
    __builtin_amdgcn_s_setprio(0);
  }
#undef ATTN_STAGE
#undef KREAD
#undef VREAD
#undef PACK

  // ---- finalize: full row sum = this l5-half + partner half ----
  lacc += __shfl_xor(lacc, 32, 64);
  const float rl = 1.f / lacc;
  const int t = q0 + (w << 5) + l31;

  // ---- epilogue: uoT[b][t][h*128+e] = bf16(u * o / l) ----
#pragma unroll
  for (int eb = 0; eb < 4; ++eb) {
#pragma unroll
    for (int g = 0; g < 4; ++g) {
      const int e4 = (eb << 5) + (g << 3) + (l5 << 2);
      const int eg = (h << 7) + e4;
      ushort4 outv;
      unsigned short* op = (unsigned short*)&outv;
#pragma unroll
      for (int j = 0; j < 4; ++j) {
        const int i = (g << 2) + j;
        const float oo = o[eb][i] * rl;
        const float uu = b2f(u[((((size_t)b << 10) + eg + j) << 10) + t]);
        op[j] = f2b(oo * uu);
      }
      *(ushort4*)(uoT + ((((size_t)b << 10) + t) << 10) + eg) = outv;
    }
  }
}

// ---------------- GEMM C: out^T = uoT(1024x1024) @ W_out^T, +bias+residual -> y(bf16) ----------------
__global__ __launch_bounds__(256) void gemm_c_kernel(const unsigned short* __restrict__ uoT,
                                                     const unsigned short* __restrict__ WoutB,
                                                     const float* __restrict__ x,
                                                     const float* __restrict__ b_out,
                                                     unsigned short* __restrict__ y) {
  __shared__ __align__(16) unsigned short lsA[12288];
  __shared__ __align__(16) unsigned short lsB[12288];
  // XCD swizzle: 256 = 8 x 32
  const int bid = ((blockIdx.x & 7) * 32) + (blockIdx.x >> 3);
  const int b = bid >> 5;
  const int rem = bid & 31;
  const int m0 = (rem >> 2) << 7;  // t tile
  const int n0 = (rem & 3) << 7;   // c tile
  f32x4 acc[4][4];
  const f32x4 z4 = {0.f, 0.f, 0.f, 0.f};
#pragma unroll
  for (int mi = 0; mi < 4; ++mi)
#pragma unroll
    for (int ni = 0; ni < 4; ++ni) acc[mi][ni] = z4;

  const unsigned short* Ag = uoT + ((size_t)b << 20) + ((size_t)m0 << 10);
  const unsigned short* Bg = WoutB + ((size_t)n0 << 10);
  gemm_bt_core(Ag, Bg, 1024, 1024, 1024, lsA, lsB, acc);

  const int lane = threadIdx.x & 63;
  const int w = threadIdx.x >> 6;
  const int wr = w >> 1, wc = w & 1;
#pragma unroll
  for (int mi = 0; mi < 4; ++mi) {
    const int t4 = m0 + (wr << 6) + (mi << 4) + ((lane >> 4) << 2);
#pragma unroll
    for (int ni = 0; ni < 4; ++ni) {
      const int c = n0 + (wc << 6) + (ni << 4) + (lane & 15);
      const size_t base = ((((size_t)b << 9) + c) << 10) + t4;
      const f32x4 xv = *(const f32x4*)(x + base);
      const float bo = b_out[c];
      ushort4 ov;
      unsigned short* op = (unsigned short*)&ov;
#pragma unroll
      for (int i = 0; i < 4; ++i) op[i] = f2b(acc[mi][ni][i] + bo + xv[i]);
      *(ushort4*)(y + base) = ov;
    }
  }
}

// ---------------- RMSNorm over C per (b,t): y bf16 in, f32 out ----------------
__global__ __launch_bounds__(256) void rms_kernel(const unsigned short* __restrict__ y,
                                                  const float* __restrict__ gamma,
                                                  float* __restrict__ out) {
  __shared__ float part[8][32];
  __shared__ float rmsv[32];
  const int bid = blockIdx.x;
  const int b = bid >> 5;
  const int t0 = (bid & 31) << 5;  // 32 t per block
  const int tid = threadIdx.x;
  const int tt = tid & 31, cg = tid >> 5;  // cg 0..7, 64 c each
  const int t = t0 + tt;
  float vals[64];
  float ss = 0.f;
#pragma unroll
  for (int ci = 0; ci < 64; ++ci) {
    const int c = (cg << 6) + ci;
    const float vv = b2f(y[((((size_t)b << 9) + c) << 10) + t]);
    vals[ci] = vv;
    ss += vv * vv;
  }
  part[cg][tt] = ss;
  __syncthreads();
  if (tid < 32) {
    float tot = 0.f;
#pragma unroll
    for (int g = 0; g < 8; ++g) tot += part[g][tid];
    rmsv[tid] = rsqrtf(tot / 512.f + 1e-5f);
  }
  __syncthreads();
  const float rm = rmsv[tt];
#pragma unroll
  for (int ci = 0; ci < 64; ++ci) {
    const int c = (cg << 6) + ci;
    out[((((size_t)b << 9) + c) << 10) + t] = vals[ci] * rm * gamma[c];
  }
}

extern "C" void kernel_launch(void* const* d_in, const int* in_sizes, int n_in, void* d_out,
                              int out_size, void* d_ws, size_t ws_size, hipStream_t stream) {
  const float* x = (const float*)d_in[0];
  const float* W_in = (const float*)d_in[1];
  const float* b_in = (const float*)d_in[2];
  const float* W_attn = (const float*)d_in[3];
  const float* b_attn = (const float*)d_in[4];
  const float* w_q = (const float*)d_in[5];
  const float* b_q = (const float*)d_in[6];
  const float* w_k = (const float*)d_in[7];
  const float* b_k = (const float*)d_in[8];
  const float* W_out = (const float*)d_in[9];
  const float* b_out = (const float*)d_in[10];
  const float* gamma = (const float*)d_in[11];
  float* out = (float*)d_out;

  char* ws = (char*)d_ws;
  size_t off = 0;
  auto alloc = [&](size_t bytes) {
    char* p = ws + off;
    off += (bytes + 255) & ~(size_t)255;
    return p;
  };
  unsigned short* Wcat = (unsigned short*)alloc((size_t)2560 * 512 * 2);
  unsigned short* WoutB = (unsigned short*)alloc((size_t)512 * 1024 * 2);
  unsigned short* xT = (unsigned short*)alloc((size_t)8 * 1024 * 512 * 2);
  unsigned short* u = (unsigned short*)alloc((size_t)8 * 1024 * 1024 * 2);
  unsigned short* v = (unsigned short*)alloc((size_t)8 * 1024 * 1024 * 2);
  unsigned short* qT = (unsigned short*)alloc((size_t)8 * 8 * 1024 * 64 * 2);
  unsigned short* kT = (unsigned short*)alloc((size_t)8 * 8 * 1024 * 64 * 2);
  unsigned short* uoT = (unsigned short*)alloc((size_t)8 * 1024 * 1024 * 2);
  unsigned short* y = (unsigned short*)alloc((size_t)8 * 512 * 1024 * 2);
  if (off > ws_size) return;  // fail visibly (poisoned output)

  prep_kernel<<<4992, 256, 0, stream>>>(x, W_in, W_attn, W_out, Wcat, WoutB, xT);
  gemm_a_kernel<<<1280, 256, 0, stream>>>(Wcat, xT, b_in, b_attn, w_q, b_q, w_k, b_k, u, v, qT,
                                          kT);
  attn_kernel<<<512, 256, 0, stream>>>(qT, kT, v, u, uoT);
  gemm_c_kernel<<<256, 256, 0, stream>>>(uoT, WoutB, x, b_out, y);
  rms_kernel<<<256, 256, 0, stream>>>(y, gamma, out);
}

// Round 19
// 120.902 us; speedup vs baseline: 1.0592x; 1.0009x over previous
//
#include <hip/hip_runtime.h>

typedef __attribute__((ext_vector_type(8))) short short8;
typedef __attribute__((ext_vector_type(4))) float f32x4;
typedef __attribute__((ext_vector_type(16))) float f32x16;

__device__ __forceinline__ unsigned short f2b(float f) {
  union { float f; unsigned u; } x; x.f = f;
  unsigned r = (x.u + 0x7fffu + ((x.u >> 16) & 1u)) >> 16;
  return (unsigned short)r;
}
__device__ __forceinline__ float b2f(unsigned short b) {
  union { unsigned u; float f; } x; x.u = ((unsigned)b) << 16;
  return x.f;
}
__device__ __forceinline__ unsigned cvtpk(float lo, float hi) {
  unsigned r;
  asm("v_cvt_pk_bf16_f32 %0, %1, %2" : "=v"(r) : "v"(lo), "v"(hi));
  return r;
}
__device__ __forceinline__ void plswap(unsigned& a, unsigned& b) {
  asm volatile("v_permlane32_swap_b32 %0, %1" : "+v"(a), "+v"(b));
}

#define GLDS16(gp, lp)                                                                  \
  __builtin_amdgcn_global_load_lds((const __attribute__((address_space(1))) void*)(gp), \
                                   (__attribute__((address_space(3))) void*)(lp), 16, 0, 0)

// ---------------- fused prep: weight conversion + x transpose ----------------
__global__ __launch_bounds__(256) void prep_kernel(const float* __restrict__ x,
                                                   const float* __restrict__ W_in,
                                                   const float* __restrict__ W_attn,
                                                   const float* __restrict__ W_out,
                                                   unsigned short* __restrict__ Wcat,
                                                   unsigned short* __restrict__ WoutB,
                                                   unsigned short* __restrict__ xT) {
  if (blockIdx.x < 4096) {
    // transpose: xT[b][t][c] = bf16(x[b][c][t]); b = bid&7 aligns batch to XCD
    __shared__ float tile[32][33];
    const int bid = blockIdx.x;
    const int b = bid & 7;
    const int rem = bid >> 3;
    const int c0 = (rem >> 5) << 5;
    const int t0 = (rem & 31) << 5;
    const int tj = threadIdx.x & 31, ti = threadIdx.x >> 5;  // ti 0..7
#pragma unroll
    for (int r = 0; r < 32; r += 8)
      tile[ti + r][tj] = x[(((size_t)b << 9) + c0 + ti + r) * 1024 + t0 + tj];
    __syncthreads();
#pragma unroll
    for (int r = 0; r < 32; r += 8)
      xT[(((size_t)b << 10) + t0 + ti + r) * 512 + c0 + tj] = f2b(tile[tj][ti + r]);
  } else {
    const int n1 = 2048 * 512, n2 = 512 * 512, n3 = 512 * 1024;
    for (int i = (blockIdx.x - 4096) * 256 + threadIdx.x; i < n1 + n2 + n3; i += 896 * 256) {
      if (i < n1) Wcat[i] = f2b(W_in[i]);
      else if (i < n1 + n2) Wcat[i] = f2b(W_attn[i - n1]);
      else WoutB[i - n1 - n2] = f2b(W_out[i - n1 - n2]);
    }
  }
}

// ---------------- shared GEMM core: 128x128 tile, BK=32, 4 waves, 3-buf, 1 barrier/step ----------------
// Slot swizzle (verified: conflicts 2.6M -> 0): LDS[row][slot s] holds global k-slot
// s ^ ((row>>1)&3); stage pre-swizzles the GLOBAL source col (dest linear, as
// global_load_lds requires); reads XOR the same. Counted vmcnt(4) keeps tile t+1's
// loads in flight across the barrier (T4).
__device__ __forceinline__ void gemm_stage(const unsigned short* Ag, const unsigned short* Bg,
                                           int lda, int ldb, int k0, unsigned short* lsA,
                                           unsigned short* lsB, int buf, int sr, int sk,
                                           int ldst) {
  const int bb = buf * 8192;  // bytes per buffer
  GLDS16(Ag + (size_t)sr * lda + k0 + sk, (char*)lsA + bb + ldst);
  GLDS16(Ag + (size_t)(sr + 64) * lda + k0 + sk, (char*)lsA + bb + 4096 + ldst);
  GLDS16(Bg + (size_t)sr * ldb + k0 + sk, (char*)lsB + bb + ldst);
  GLDS16(Bg + (size_t)(sr + 64) * ldb + k0 + sk, (char*)lsB + bb + 4096 + ldst);
}

__device__ __forceinline__ void gemm_bt_core(const unsigned short* __restrict__ Ag,
                                             const unsigned short* __restrict__ Bg, int lda,
                                             int ldb, int K, unsigned short* lsA,
                                             unsigned short* lsB, f32x4 acc[4][4]) {
  const int tid = threadIdx.x;
  const int lane = tid & 63;
  const int w = tid >> 6;
  const int wr = w >> 1, wc = w & 1;
  const int sr = tid >> 2;  // staging row 0..63 (row sr and sr+64 share (sr>>1)&3 mod 4)
  const int sk = (((tid & 3) ^ ((sr >> 1) & 3)) << 3);  // swizzled global k-slot (elems)
  const int ldst = (tid >> 6) << 10;  // wave-uniform LDS byte base

  const int nt = K >> 5;
  int c0b = 0, c1b = 1, c2b = 2;
  gemm_stage(Ag, Bg, lda, ldb, 0, lsA, lsB, 0, sr, sk, ldst);
  gemm_stage(Ag, Bg, lda, ldb, 32, lsA, lsB, 1, sr, sk, ldst);
  for (int t = 0; t < nt; ++t) {
    if (t + 1 < nt) {
      asm volatile("s_waitcnt vmcnt(4)" ::: "memory");  // tile t landed (t+1 in flight)
    } else {
      asm volatile("s_waitcnt vmcnt(0)" ::: "memory");
    }
    __builtin_amdgcn_s_barrier();  // tile t visible block-wide; t-1 reads done
    if (t + 2 < nt)
      gemm_stage(Ag, Bg, lda, ldb, (t + 2) << 5, lsA, lsB, c2b, sr, sk, ldst);
    short8 af[4], bfr[4];
    const int bb = c0b * 8192;
    const int ko = (lane >> 4) << 4;  // byte slot within 64B row
    const int ra = (wr << 6) + (lane & 15);
    const int rb = (wc << 6) + (lane & 15);
#pragma unroll
    for (int mi = 0; mi < 4; ++mi) {
      const int rowA = ra + (mi << 4);
      af[mi] = *(const short8*)((const char*)lsA + bb + (rowA << 6) +
                                (ko ^ (((rowA >> 1) & 3) << 4)));
    }
#pragma unroll
    for (int ni = 0; ni < 4; ++ni) {
      const int rowB = rb + (ni << 4);
      bfr[ni] = *(const short8*)((const char*)lsB + bb + (rowB << 6) +
                                 (ko ^ (((rowB >> 1) & 3) << 4)));
    }
#pragma unroll
    for (int mi = 0; mi < 4; ++mi)
#pragma unroll
      for (int ni = 0; ni < 4; ++ni)
        acc[mi][ni] =
            __builtin_amdgcn_mfma_f32_16x16x32_bf16(af[mi], bfr[ni], acc[mi][ni], 0, 0, 0);
    const int tmp = c0b; c0b = c1b; c1b = c2b; c2b = tmp;
  }
}

// ---------------- GEMM A: [W_in;W_attn](2560x512) @ x[b](512x1024) ----------------
__global__ __launch_bounds__(256) void gemm_a_kernel(
    const unsigned short* __restrict__ Wcat, const unsigned short* __restrict__ xT,
    const float* __restrict__ b_in, const float* __restrict__ b_attn,
    const float* __restrict__ w_q, const float* __restrict__ b_q, const float* __restrict__ w_k,
    const float* __restrict__ b_k, unsigned short* __restrict__ u, unsigned short* __restrict__ v,
    unsigned short* __restrict__ qT, unsigned short* __restrict__ kT) {
  __shared__ __align__(16) unsigned short lsA[12288];  // 3 x 8KB
  __shared__ __align__(16) unsigned short lsB[12288];
  // XCD swizzle: 1280 = 8 XCDs x 160; each XCD owns one batch b (W+x ~3.6MB fits L2)
  const int bid = ((blockIdx.x & 7) * 160) + (blockIdx.x >> 3);
  const int b = bid / 160;
  const int rem = bid % 160;
  const int m0 = (rem >> 3) << 7;
  const int n0 = (rem & 7) << 7;
  f32x4 acc[4][4];
  const f32x4 z4 = {0.f, 0.f, 0.f, 0.f};
#pragma unroll
  for (int mi = 0; mi < 4; ++mi)
#pragma unroll
    for (int ni = 0; ni < 4; ++ni) acc[mi][ni] = z4;

  const unsigned short* Ag = Wcat + (size_t)m0 * 512;
  const unsigned short* Bg = xT + ((size_t)b << 19) + ((size_t)n0 << 9);
  gemm_bt_core(Ag, Bg, 512, 512, 512, lsA, lsB, acc);

  const int lane = threadIdx.x & 63;
  const int w = threadIdx.x >> 6;
  const int wr = w >> 1, wc = w & 1;
#pragma unroll
  for (int mi = 0; mi < 4; ++mi) {
    const int row0 = m0 + (wr << 6) + (mi << 4) + ((lane >> 4) << 2);
#pragma unroll
    for (int ni = 0; ni < 4; ++ni) {
      const int col = n0 + (wc << 6) + (ni << 4) + (lane & 15);
      if (row0 < 2048) {
#pragma unroll
        for (int i = 0; i < 4; ++i) {
          const int row = row0 + i;
          const float s = acc[mi][ni][i] + b_in[row];
          const float r = s / (1.f + __expf(-s));  // silu
          if (row < 1024)
            u[((((size_t)b << 10) + row) << 10) + col] = f2b(r);
          else
            v[((((size_t)b << 10) + (row - 1024)) << 10) + col] = f2b(r);
        }
      } else {
        const int c0 = row0 - 2048;
        ushort4 qv, kv;
        unsigned short* qp = (unsigned short*)&qv;
        unsigned short* kp = (unsigned short*)&kv;
#pragma unroll
        for (int i = 0; i < 4; ++i) {
          const int c = c0 + i;
          const float z = acc[mi][ni][i] + b_attn[c];
          qp[i] = f2b(z * w_q[c] + b_q[c]);
          kp[i] = f2b(z * w_k[c] + b_k[c]);
        }
        const int h = c0 >> 6, d = c0 & 63;
        const size_t base = ((((size_t)b * 8 + h) << 10) + col) * 64 + d;
        *(ushort4*)(qT + base) = qv;
        *(ushort4*)(kT + base) = kv;
      }
    }
  }
}

// ---------------- flash attention v6: T15 double-pipeline (PV consumes prev tile's P) ----------------
__global__ __launch_bounds__(256, 2) void attn_kernel(const unsigned short* __restrict__ qT,
                                                      const unsigned short* __restrict__ kT,
                                                      const unsigned short* __restrict__ v,
                                                      const unsigned short* __restrict__ u,
                                                      unsigned short* __restrict__ uoT) {
  __shared__ __align__(16) unsigned short Kls[3 * 4096];  // 3 x [64 k][64 d] swizzled
  __shared__ __align__(16) unsigned short Vls[3 * 8192];  // 3 x [128 e][64 t] swizzled
  const float SCALE2 = 0.20037430567f;  // (log(1024)/log(512)/sqrt(64)) * log2(e)
  const int bx = blockIdx.x;
  const int xcd = bx & 7, idx = bx >> 3;  // idx 0..63
  const int bh = (xcd << 3) + (idx & 7);
  const int qb = idx >> 3;  // 0..7
  const int b = bh >> 3, h = bh & 7;
  const int tid = threadIdx.x;
  const int lane = tid & 63;
  const int w = tid >> 6;  // qw 0..3
  const int l5 = lane >> 5;
  const int l31 = lane & 31;
  const int q0 = qb << 7;

  const unsigned short* qh = qT + ((size_t)bh << 16);
  const unsigned short* kh = kT + ((size_t)bh << 16);
  const unsigned short* vh = v + ((((size_t)b << 10) + (h << 7)) << 10);

  short8 qf[4];
#pragma unroll
  for (int ds = 0; ds < 4; ++ds)
    qf[ds] = *(const short8*)(qh + (size_t)(q0 + (w << 5) + l31) * 64 + (ds << 4) + (l5 << 3));

  f32x16 o[4];
#pragma unroll
  for (int eb = 0; eb < 4; ++eb)
#pragma unroll
    for (int i = 0; i < 16; ++i) o[eb][i] = 0.f;
  float lacc = 0.f;

  const int srow = tid >> 3;                         // 0..31
  const int scol = (((tid & 7) ^ (srow & 7)) << 3);  // pre-swizzled src col (elems)

#define ATTN_STAGE(buf, kt)                                                            \
  {                                                                                    \
    const int t2 = (kt) << 6;                                                          \
    char* kbase = (char*)Kls + (buf)*8192;                                             \
    char* vbase = (char*)Vls + (buf)*16384;                                            \
    GLDS16(kh + (size_t)(t2 + srow) * 64 + scol, kbase + (w << 10));                   \
    GLDS16(kh + (size_t)(t2 + 32 + srow) * 64 + scol, kbase + 4096 + (w << 10));       \
    GLDS16(vh + ((size_t)srow << 10) + t2 + scol, vbase + (w << 10));                  \
    GLDS16(vh + ((size_t)(32 + srow) << 10) + t2 + scol, vbase + 4096 + (w << 10));    \
    GLDS16(vh + ((size_t)(64 + srow) << 10) + t2 + scol, vbase + 8192 + (w << 10));    \
    GLDS16(vh + ((size_t)(96 + srow) << 10) + t2 + scol, vbase + 12288 + (w << 10));   \
  }

#define KREAD(kbp, kr, ds)                                                             \
  (*(const short8*)((kbp) + ((kr) << 7) + ((((ds) << 5) + (l5 << 4)) ^ (((kr)&7) << 4))))
#define VREAD(vbp, vrow, ks)                                                           \
  (*(const short8*)((vbp) + ((vrow) << 7) + ((((ks) << 5) + (l5 << 4)) ^ (((vrow)&7) << 4))))

#define PACK(sv, out0, out1)                                                           \
  do {                                                                                 \
    float p_[16];                                                                      \
    _Pragma("unroll") for (int i_ = 0; i_ < 16; ++i_) {                                \
      p_[i_] = exp2f(sv[i_] * SCALE2);                                                 \
      lacc += p_[i_];                                                                  \
    }                                                                                  \
    unsigned W00 = cvtpk(p_[0], p_[1]), W01 = cvtpk(p_[2], p_[3]);                     \
    unsigned W10 = cvtpk(p_[4], p_[5]), W11 = cvtpk(p_[6], p_[7]);                     \
    unsigned W20 = cvtpk(p_[8], p_[9]), W21 = cvtpk(p_[10], p_[11]);                   \
    unsigned W30 = cvtpk(p_[12], p_[13]), W31 = cvtpk(p_[14], p_[15]);                 \
    unsigned a_ = W10, b_ = W00;                                                       \
    plswap(a_, b_);                                                                    \
    (out0).u4[0] = b_; (out0).u4[2] = a_;                                              \
    unsigned c_ = W11, d_ = W01;                                                       \
    plswap(c_, d_);                                                                    \
    (out0).u4[1] = d_; (out0).u4[3] = c_;                                              \
    unsigned e_ = W30, f_ = W20;                                                       \
    plswap(e_, f_);                                                                    \
    (out1).u4[0] = f_; (out1).u4[2] = e_;                                              \
    unsigned g_ = W31, h_ = W21;                                                       \
    plswap(g_, h_);                                                                    \
    (out1).u4[1] = h_; (out1).u4[3] = g_;                                              \
  } while (0)

  union U8 { short8 s8; unsigned u4[4]; };
  U8 pfP[4];

  ATTN_STAGE(0, 0);
  ATTN_STAGE(1, 1);

  // ---- iter 0: QK(0) + pack only ----
  asm volatile("s_waitcnt vmcnt(6)" ::: "memory");
  __builtin_amdgcn_s_barrier();
  {
    const char* kb = (const char*)Kls;
    f32x16 s0, s1;
#pragma unroll
    for (int i = 0; i < 16; ++i) { s0[i] = 0.f; s1[i] = 0.f; }
    __builtin_amdgcn_s_setprio(1);
#pragma unroll
    for (int ds = 0; ds < 4; ++ds) {
      short8 kfA = KREAD(kb, l31, ds);
      s0 = __builtin_amdgcn_mfma_f32_32x32x16_bf16(kfA, qf[ds], s0, 0, 0, 0);
      short8 kfB = KREAD(kb, 32 + l31, ds);
      s1 = __builtin_amdgcn_mfma_f32_32x32x16_bf16(kfB, qf[ds], s1, 0, 0, 0);
    }
    __builtin_amdgcn_s_setprio(0);
    PACK(s0, pfP[0], pfP[1]);
    PACK(s1, pfP[2], pfP[3]);
  }
  __builtin_amdgcn_s_barrier();
  ATTN_STAGE(2, 2);

  int ck = 1, cv = 0;  // ck = kt%3, cv = (kt-1)%3
  for (int kt = 1; kt < 16; ++kt) {
    if (kt < 15) {
      asm volatile("s_waitcnt vmcnt(6)" ::: "memory");  // tile kt landed
    } else {
      asm volatile("s_waitcnt vmcnt(0)" ::: "memory");
    }
    __builtin_amdgcn_s_barrier();  // K/V[kt] visible to all waves

    const char* kb = (const char*)Kls + ck * 8192;
    const char* vb = (const char*)Vls + cv * 16384;

    // preload K fragments
    short8 kfA[4], kfB[4];
#pragma unroll
    for (int ds = 0; ds < 4; ++ds) {
      kfA[ds] = KREAD(kb, l31, ds);
      kfB[ds] = KREAD(kb, 32 + l31, ds);
    }

    // ---- interleaved: QK(kt) (8 MFMA) || PV(kt-1) (16 MFMA) ----
    f32x16 s0, s1;
#pragma unroll
    for (int i = 0; i < 16; ++i) { s0[i] = 0.f; s1[i] = 0.f; }
    __builtin_amdgcn_s_setprio(1);
#pragma unroll
    for (int ks = 0; ks < 4; ++ks) {
      s0 = __builtin_amdgcn_mfma_f32_32x32x16_bf16(kfA[ks], qf[ks], s0, 0, 0, 0);
      s1 = __builtin_amdgcn_mfma_f32_32x32x16_bf16(kfB[ks], qf[ks], s1, 0, 0, 0);
#pragma unroll
      for (int eb = 0; eb < 4; ++eb) {
        short8 vf = VREAD(vb, (eb << 5) + l31, ks);
        o[eb] = __builtin_amdgcn_mfma_f32_32x32x16_bf16(vf, pfP[ks].s8, o[eb], 0, 0, 0);
      }
    }
    __builtin_amdgcn_s_setprio(0);

    // ---- pack(kt) -> pfP (feeds next iter's PV) ----
    U8 pfN[4];
    PACK(s0, pfN[0], pfN[1]);
    PACK(s1, pfN[2], pfN[3]);
#pragma unroll
    for (int i = 0; i < 4; ++i) pfP[i] = pfN[i];

    if (kt + 2 < 16) {
      __builtin_amdgcn_s_barrier();  // all waves done reading V[kt-1] / K[kt-1]
      ATTN_STAGE(cv, kt + 2);        // (kt+2)%3 == cv
    }
    const int third = 3 - ck - cv;
    cv = ck;
    ck = third;
  }

  // ---- tail: PV(15) ----
  {
    const char* vb = (const char*)Vls + cv * 16384;
    __builtin_amdgcn_s_setprio(1);
#pragma unroll
    for (int ks = 0; ks < 4; ++ks) {
#pragma unroll
      for (int eb = 0; eb < 4; ++eb) {
        short8 vf = VREAD(vb, (eb << 5) + l31, ks);
        o[eb] = __builtin_amdgcn_mfma_f32_32x32x16_bf16(vf, pfP[ks].s8, o[eb], 0, 0, 0);
      }
    }
    __builtin_amdgcn_s_setprio(0);
  }
#undef ATTN_STAGE
#undef KREAD
#undef VREAD
#undef PACK

  // ---- finalize: full row sum = this l5-half + partner half ----
  lacc += __shfl_xor(lacc, 32, 64);
  const float rl = 1.f / lacc;
  const int t = q0 + (w << 5) + l31;

  // ---- epilogue: uoT[b][t][h*128+e] = bf16(u * o / l) ----
#pragma unroll
  for (int eb = 0; eb < 4; ++eb) {
#pragma unroll
    for (int g = 0; g < 4; ++g) {
      const int e4 = (eb << 5) + (g << 3) + (l5 << 2);
      const int eg = (h << 7) + e4;
      ushort4 outv;
      unsigned short* op = (unsigned short*)&outv;
#pragma unroll
      for (int j = 0; j < 4; ++j) {
        const int i = (g << 2) + j;
        const float oo = o[eb][i] * rl;
        const float uu = b2f(u[((((size_t)b << 10) + eg + j) << 10) + t]);
        op[j] = f2b(oo * uu);
      }
      *(ushort4*)(uoT + ((((size_t)b << 10) + t) << 10) + eg) = outv;
    }
  }
}

// ---------------- GEMM C: out^T = uoT(1024x1024) @ W_out^T, +bias+residual -> y(bf16) ----------------
__global__ __launch_bounds__(256) void gemm_c_kernel(const unsigned short* __restrict__ uoT,
                                                     const unsigned short* __restrict__ WoutB,
                                                     const float* __restrict__ x,
                                                     const float* __restrict__ b_out,
                                                     unsigned short* __restrict__ y) {
  __shared__ __align__(16) unsigned short lsA[12288];
  __shared__ __align__(16) unsigned short lsB[12288];
  // XCD swizzle: 256 = 8 x 32
  const int bid = ((blockIdx.x & 7) * 32) + (blockIdx.x >> 3);
  const int b = bid >> 5;
  const int rem = bid & 31;
  const int m0 = (rem >> 2) << 7;  // t tile
  const int n0 = (rem & 3) << 7;   // c tile
  f32x4 acc[4][4];
  const f32x4 z4 = {0.f, 0.f, 0.f, 0.f};
#pragma unroll
  for (int mi = 0; mi < 4; ++mi)
#pragma unroll
    for (int ni = 0; ni < 4; ++ni) acc[mi][ni] = z4;

  const unsigned short* Ag = uoT + ((size_t)b << 20) + ((size_t)m0 << 10);
  const unsigned short* Bg = WoutB + ((size_t)n0 << 10);
  gemm_bt_core(Ag, Bg, 1024, 1024, 1024, lsA, lsB, acc);

  const int lane = threadIdx.x & 63;
  const int w = threadIdx.x >> 6;
  const int wr = w >> 1, wc = w & 1;
#pragma unroll
  for (int mi = 0; mi < 4; ++mi) {
    const int t4 = m0 + (wr << 6) + (mi << 4) + ((lane >> 4) << 2);
#pragma unroll
    for (int ni = 0; ni < 4; ++ni) {
      const int c = n0 + (wc << 6) + (ni << 4) + (lane & 15);
      const size_t base = ((((size_t)b << 9) + c) << 10) + t4;
      const f32x4 xv = *(const f32x4*)(x + base);
      const float bo = b_out[c];
      ushort4 ov;
      unsigned short* op = (unsigned short*)&ov;
#pragma unroll
      for (int i = 0; i < 4; ++i) op[i] = f2b(acc[mi][ni][i] + bo + xv[i]);
      *(ushort4*)(y + base) = ov;
    }
  }
}

// ---------------- RMSNorm over C per (b,t): y bf16 in, f32 out ----------------
__global__ __launch_bounds__(256) void rms_kernel(const unsigned short* __restrict__ y,
                                                  const float* __restrict__ gamma,
                                                  float* __restrict__ out) {
  __shared__ float part[8][32];
  __shared__ float rmsv[32];
  const int bid = blockIdx.x;
  const int b = bid >> 5;
  const int t0 = (bid & 31) << 5;  // 32 t per block
  const int tid = threadIdx.x;
  const int tt = tid & 31, cg = tid >> 5;  // cg 0..7, 64 c each
  const int t = t0 + tt;
  float vals[64];
  float ss = 0.f;
#pragma unroll
  for (int ci = 0; ci < 64; ++ci) {
    const int c = (cg << 6) + ci;
    const float vv = b2f(y[((((size_t)b << 9) + c) << 10) + t]);
    vals[ci] = vv;
    ss += vv * vv;
  }
  part[cg][tt] = ss;
  __syncthreads();
  if (tid < 32) {
    float tot = 0.f;
#pragma unroll
    for (int g = 0; g < 8; ++g) tot += part[g][tid];
    rmsv[tid] = rsqrtf(tot / 512.f + 1e-5f);
  }
  __syncthreads();
  const float rm = rmsv[tt];
#pragma unroll
  for (int ci = 0; ci < 64; ++ci) {
    const int c = (cg << 6) + ci;
    out[((((size_t)b << 9) + c) << 10) + t] = vals[ci] * rm * gamma[c];
  }
}

extern "C" void kernel_launch(void* const* d_in, const int* in_sizes, int n_in, void* d_out,
                              int out_size, void* d_ws, size_t ws_size, hipStream_t stream) {
  const float* x = (const float*)d_in[0];
  const float* W_in = (const float*)d_in[1];
  const float* b_in = (const float*)d_in[2];
  const float* W_attn = (const float*)d_in[3];
  const float* b_attn = (const float*)d_in[4];
  const float* w_q = (const float*)d_in[5];
  const float* b_q = (const float*)d_in[6];
  const float* w_k = (const float*)d_in[7];
  const float* b_k = (const float*)d_in[8];
  const float* W_out = (const float*)d_in[9];
  const float* b_out = (const float*)d_in[10];
  const float* gamma = (const float*)d_in[11];
  float* out = (float*)d_out;

  char* ws = (char*)d_ws;
  size_t off = 0;
  auto alloc = [&](size_t bytes) {
    char* p = ws + off;
    off += (bytes + 255) & ~(size_t)255;
    return p;
  };
  unsigned short* Wcat = (unsigned short*)alloc((size_t)2560 * 512 * 2);
  unsigned short* WoutB = (unsigned short*)alloc((size_t)512 * 1024 * 2);
  unsigned short* xT = (unsigned short*)alloc((size_t)8 * 1024 * 512 * 2);
  unsigned short* u = (unsigned short*)alloc((size_t)8 * 1024 * 1024 * 2);
  unsigned short* v = (unsigned short*)alloc((size_t)8 * 1024 * 1024 * 2);
  unsigned short* qT = (unsigned short*)alloc((size_t)8 * 8 * 1024 * 64 * 2);
  unsigned short* kT = (unsigned short*)alloc((size_t)8 * 8 * 1024 * 64 * 2);
  unsigned short* uoT = (unsigned short*)alloc((size_t)8 * 1024 * 1024 * 2);
  unsigned short* y = (unsigned short*)alloc((size_t)8 * 512 * 1024 * 2);
  if (off > ws_size) return;  // fail visibly (poisoned output)

  prep_kernel<<<4992, 256, 0, stream>>>(x, W_in, W_attn, W_out, Wcat, WoutB, xT);
  gemm_a_kernel<<<1280, 256, 0, stream>>>(Wcat, xT, b_in, b_attn, w_q, b_q, w_k, b_k, u, v, qT,
                                          kT);
  attn_kernel<<<512, 256, 0, stream>>>(qT, kT, v, u, uoT);
  gemm_c_kernel<<<256, 256, 0, stream>>>(uoT, WoutB, x, b_out, y);
  rms_kernel<<<256, 256, 0, stream>>>(y, gamma, out);
}